// Round 10
// baseline (188.690 us; speedup 1.0000x reference)
//
#include <hip/hip_runtime.h>

// CrossAttention B=16, N1=N2=2048, D=512, L=256 — algebraic restructure +
// fused flash-style S~/U kernel with counted-vmcnt (T4) 4-buffer pipeline:
//   W' = Wk·Wq^T, bq' = bq·Wk^T; Q' = X1·W'^T + bq'   [32768x256]
//   fused: per 128-row tile, 64 steps of 32 keys, stages 2-deep in flight
//          (vmcnt(8), never drained to 0 in the loop)
//   out = inv·(U·Wv) + bv
// Unfused GEMMs: proven 256-row 8-wave counted-vmcnt templates.

#define DIMD 512
#define LENL 256
#define BATCH 16
#define NQ 2048
#define NKV 2048

using bf16x8 = __attribute__((ext_vector_type(8))) __bf16;
using f32x4  = __attribute__((ext_vector_type(4))) float;
typedef unsigned short u16;

__device__ __forceinline__ u16 f2bf(float f) {
  union { float f; unsigned u; } x; x.f = f;
  return (u16)((x.u + 0x7fffu + ((x.u >> 16) & 1u)) >> 16);
}
__device__ __forceinline__ float bf2f(u16 b) {
  union { unsigned u; float f; } x; x.u = ((unsigned)b) << 16;
  return x.f;
}

__global__ __launch_bounds__(256) void k_cvt(const float* __restrict__ src,
                                             u16* __restrict__ dst, int n4) {
  int i = blockIdx.x * blockDim.x + threadIdx.x;
  int stride = gridDim.x * blockDim.x;
  for (; i < n4; i += stride) {
    float4 v = ((const float4*)src)[i];
    ushort4 o;
    o.x = f2bf(v.x); o.y = f2bf(v.y); o.z = f2bf(v.z); o.w = f2bf(v.w);
    ((ushort4*)dst)[i] = o;
  }
}

__global__ __launch_bounds__(256) void k_transpose(const float* __restrict__ W,
                                                   u16* __restrict__ WT,
                                                   int K, int N) {
  __shared__ float t[32][33];
  int bx = blockIdx.x * 32;
  int by = blockIdx.y * 32;
  int tx = threadIdx.x, ty = threadIdx.y;  // (32,8)
#pragma unroll
  for (int i = 0; i < 4; i++)
    t[ty + 8 * i][tx] = W[(size_t)(by + ty + 8 * i) * N + (bx + tx)];
  __syncthreads();
#pragma unroll
  for (int i = 0; i < 4; i++)
    WT[(size_t)(bx + ty + 8 * i) * K + (by + tx)] = f2bf(t[tx][ty + 8 * i]);
}

// fused: in2 f32 [z][2048][256] -> A2 bf16 (same layout) + TX2 bf16 [z][256][2048]
__global__ __launch_bounds__(256) void k_cvt_t(const float* __restrict__ in2,
                                               u16* __restrict__ A2,
                                               u16* __restrict__ TX2) {
  __shared__ u16 t[32][33];
  int bx = blockIdx.x * 32;  // L (256)
  int by = blockIdx.y * 32;  // keys (2048)
  long z = blockIdx.z;
  const float* s = in2 + z * (2048L * 256);
  u16* a = A2 + z * (2048L * 256);
  u16* d = TX2 + z * (256L * 2048);
  int tx = threadIdx.x, ty = threadIdx.y;  // (32,8)
#pragma unroll
  for (int i = 0; i < 4; i++) {
    u16 v = f2bf(s[(size_t)(by + ty + 8 * i) * 256 + (bx + tx)]);
    a[(size_t)(by + ty + 8 * i) * 256 + (bx + tx)] = v;
    t[ty + 8 * i][tx] = v;
  }
  __syncthreads();
#pragma unroll
  for (int i = 0; i < 4; i++)
    d[(size_t)(bx + ty + 8 * i) * 2048 + (by + tx)] = t[tx][ty + 8 * i];
}

__global__ __launch_bounds__(256) void k_bqp(const float* __restrict__ bq,
                                             const float* __restrict__ Wk,
                                             float* __restrict__ bqp) {
  int n = threadIdx.x;
  float s = 0.f;
  for (int o = 0; o < 512; o += 4) {
    float4 w = *(const float4*)&Wk[(size_t)n * 512 + o];
    float4 b = *(const float4*)&bq[o];
    s += w.x * b.x + w.y * b.y + w.z * b.z + w.w * b.w;
  }
  bqp[n] = s;
}

__device__ __forceinline__ void gl_lds16(const void* g, void* l) {
  __builtin_amdgcn_global_load_lds(
      (const __attribute__((address_space(1))) void*)g,
      (__attribute__((address_space(3))) void*)l, 16, 0, 0);
}

__device__ __forceinline__ void xcd_swz(int& bx, int& by, int& bz) {
  const int nx = gridDim.x, ny = gridDim.y, nz = gridDim.z;
  const long nwg = (long)nx * ny * nz;
  if (nwg & 7) return;
  long lin = (long)bx + (long)nx * ((long)by + (long)ny * bz);
  const long q = nwg >> 3;
  const long nl = (lin & 7) * q + (lin >> 3);
  bx = (int)(nl % nx);
  long r2 = nl / nx;
  by = (int)(r2 % ny);
  bz = (int)(r2 / ny);
}

#define MF(a, b, c) __builtin_amdgcn_mfma_f32_16x16x32_bf16(a, b, c, 0, 0, 0)

// ================== fused S~ / U kernel (counted-vmcnt, 4-buffer) ============
// Block: 128 q-rows x batch. 64 steps of 32 keys. Per step:
//  STG(i+2) -> vmcnt(8) -> B1 -> QK (waves: rq4 x kh2, 16k x 32r) -> exp ->
//  S b64 writes -> lgkmcnt(0) -> B2 -> PV (waves: wr2 x wc4, 64r x 64c).
// LDS: X2 4x16K [0,64K) | TX2 4x16K [64K,128K) | S 8K [128K,136K) | part.
__global__ __launch_bounds__(512, 2) void k_fused_su(
    const u16* __restrict__ Qp, const u16* __restrict__ X2g,
    const u16* __restrict__ TXg, u16* __restrict__ U,
    float* __restrict__ Iv, float scale) {
  __shared__ __align__(16) char lds[139776];
  float* part = (float*)(lds + 139264);

  int bxi = blockIdx.x, byi = blockIdx.y, bzi = blockIdx.z;
  xcd_swz(bxi, byi, bzi);
  const int tid = threadIdx.x, lane = tid & 63, wid = tid >> 6;
  const int fr = lane & 15, kq = lane >> 4;
  const int fr7 = fr & 7, fr3 = fr & 3;
  const int row0 = bxi * 128;
  const long z = byi;
  const int kh = wid & 1, rq = wid >> 1;  // QK decomposition
  const int wr = wid >> 2, wc = wid & 3;  // PV decomposition

  if (tid < 128) part[tid] = 0.f;

  // Q' fragments: rows rq*32 + ni*16 + fr, l-octet (kk*4+kq)*8
  bf16x8 qf[2][8];
  {
    const u16* qb = Qp + ((long)z * 2048 + row0 + rq * 32) * 256;
#pragma unroll
    for (int ni = 0; ni < 2; ni++)
#pragma unroll
      for (int kk = 0; kk < 8; kk++)
        qf[ni][kk] =
            *(const bf16x8*)(qb + (ni * 16 + fr) * 256 + kk * 32 + kq * 8);
  }

  const u16* gX2 = X2g + (long)z * (2048 * 256);
  const u16* gTX = TXg + (long)z * (256 * 2048);
  const int xrow = tid >> 5, xs = tid & 31;  // X2 tile: 32 rows x 512B
  const int trow = tid >> 2, ts = tid & 3;   // TX2 tile: 256 rows x 64B

// stage step tile (ii) into buffer (b); 4 vm-ops per thread
#define STG(ii, b) { \
  _Pragma("unroll") for (int p = 0; p < 2; p++) { \
    const int r_ = p * 16 + xrow; \
    gl_lds16(gX2 + ((long)(ii) * 32 + r_) * 256 + (xs ^ (r_ & 7)) * 8, \
             lds + (b) * 16384 + (p * 512 + tid) * 16); } \
  _Pragma("unroll") for (int p = 0; p < 2; p++) { \
    const int r_ = p * 128 + trow; \
    gl_lds16(gTX + (long)r_ * 2048 + (ii) * 32 + (ts ^ (r_ & 3)) * 8, \
             lds + 65536 + (b) * 16384 + (p * 512 + tid) * 16); } }

  f32x4 accU[4][4];
  const f32x4 zero = {0.f, 0.f, 0.f, 0.f};
#pragma unroll
  for (int m = 0; m < 4; m++)
#pragma unroll
    for (int n = 0; n < 4; n++) accU[m][n] = zero;
  float rs0 = 0.f, rs1 = 0.f;

  STG(0, 0);
  STG(1, 1);

  for (int i = 0; i < 64; i++) {
    const int cur = i & 3;
    const int pre = (i + 2 > 63) ? 63 : i + 2;  // dup-stage tail keeps vmcnt uniform
    STG(pre, (i + 2) & 3);
    asm volatile("s_waitcnt vmcnt(8)" ::: "memory");  // stage(i) landed (2 in flight)
    __builtin_amdgcn_sched_barrier(0);
    __builtin_amdgcn_s_barrier();
    __builtin_amdgcn_sched_barrier(0);

    // ---- QK: accS[ni], C[m=key16][n=row16]; keys kh*16+kq*4+r ----
    f32x4 accS[2];
    accS[0] = zero; accS[1] = zero;
    const char* xb = lds + cur * 16384;
    __builtin_amdgcn_s_setprio(1);
#pragma unroll
    for (int kk = 0; kk < 8; kk++) {
      bf16x8 xf = *(const bf16x8*)(xb + (kh * 16 + fr) * 512 +
                                   (((kk * 4 + kq) ^ fr7) << 4));
      accS[0] = MF(xf, qf[0][kk], accS[0]);
      accS[1] = MF(xf, qf[1][kk], accS[1]);
    }
    __builtin_amdgcn_s_setprio(0);

    // ---- exp + pack + S write (row rq*32+ni*16+fr; 64B rows, slot16^fr3)
#pragma unroll
    for (int ni = 0; ni < 2; ni++) {
      u16 e[4];
      float sum4 = 0.f;
#pragma unroll
      for (int r = 0; r < 4; r++) {
        float v = accS[ni][r] * scale;
        float ef = __expf(fminf(v, 30.f));
        e[r] = f2bf(ef);
        sum4 += bf2f(e[r]);
      }
      if (ni == 0) rs0 += sum4; else rs1 += sum4;
      unsigned long long w =
          (unsigned long long)((unsigned)e[0] | ((unsigned)e[1] << 16)) |
          ((unsigned long long)((unsigned)e[2] | ((unsigned)e[3] << 16)) << 32);
      const int row = rq * 32 + ni * 16 + fr;
      const int slot16 = (kh * 2 + (kq >> 1)) ^ fr3;
      *(unsigned long long*)(lds + 131072 + row * 64 + (slot16 << 4) +
                             (kq & 1) * 8) = w;
    }
    asm volatile("s_waitcnt lgkmcnt(0)" ::: "memory");
    __builtin_amdgcn_sched_barrier(0);
    __builtin_amdgcn_s_barrier();
    __builtin_amdgcn_sched_barrier(0);

    // ---- PV: accU += S · TX2-tile (k=32, one k-step) ----
    const char* tb = lds + 65536 + cur * 16384;
    __builtin_amdgcn_s_setprio(1);
    {
      bf16x8 sf[4], tf[4];
#pragma unroll
      for (int m = 0; m < 4; m++)
        sf[m] = *(const bf16x8*)(lds + 131072 + (wr * 64 + m * 16 + fr) * 64 +
                                 ((kq ^ fr3) << 4));
#pragma unroll
      for (int n = 0; n < 4; n++)
        tf[n] = *(const bf16x8*)(tb + (wc * 64 + n * 16 + fr) * 64 +
                                 ((kq ^ fr3) << 4));
#pragma unroll
      for (int m = 0; m < 4; m++)
#pragma unroll
        for (int n = 0; n < 4; n++)
          accU[m][n] = MF(sf[m], tf[n], accU[m][n]);
    }
    __builtin_amdgcn_s_setprio(0);
    // no end-of-iter drain: next iter's B1 protects S overwrite; 4 buffers
    // make the stage target disjoint from all concurrent readers.
  }
#undef STG

  // rowsums -> Iv (block-exclusive rows)
  {
    float s0 = rs0, s1 = rs1;
    s0 += __shfl_xor(s0, 16); s0 += __shfl_xor(s0, 32);
    s1 += __shfl_xor(s1, 16); s1 += __shfl_xor(s1, 32);
    if (lane < 16) {
      atomicAdd(&part[rq * 32 + lane], s0);
      atomicAdd(&part[rq * 32 + 16 + lane], s1);
    }
  }
  __syncthreads();
  if (tid < 128) Iv[z * 2048 + row0 + tid] = 1.f / part[tid];

  // U store (unnormalized bf16; out-GEMM applies Iv)
  u16* ub = U + ((long)z * 2048 + row0) * 256;
#pragma unroll
  for (int m = 0; m < 4; m++)
#pragma unroll
    for (int n = 0; n < 4; n++) {
      const int col = wc * 64 + n * 16 + fr;
#pragma unroll
      for (int r = 0; r < 4; r++) {
        const int row = wr * 64 + m * 16 + kq * 4 + r;
        ub[row * 256 + col] = f2bf(accU[m][n][r]);
      }
    }
}

// =============== 256-row 8-wave gemm_bt (round-7 proven form) =================
#define SA(p, h, l, T) \
  gl_lds16(gA + (long)((h) * 128 + (l) * 64) * lda + (T) * 64, \
           dA + (p) * 32768 + (h) * 16384 + (l) * 8192)
#define SB(p, h, l, T) \
  gl_lds16(gB + (long)((h) * 128 + (l) * 64) * ldb + (T) * 64, \
           dB + (p) * (BNH * 16384) + (h) * 16384 + (l) * 8192)
#define RD_A(p, mh) { _Pragma("unroll") for (int m = 0; m < 4; m++) { \
    afr[m][0] = *(const bf16x8*)(lds + (p) * 32768 + aoffb + ((mh) * 64 + m * 16) * 128 + sb0); \
    afr[m][1] = *(const bf16x8*)(lds + (p) * 32768 + aoffb + ((mh) * 64 + m * 16) * 128 + sb1); } }
#define RD_B(p, nh, BF) { _Pragma("unroll") for (int n = 0; n < 2; n++) { \
    BF[n][0] = *(const bf16x8*)(lds + (p) * (BNH * 16384) + boffb + (((nh) * 2 + n) * 16) * 128 + sb0); \
    BF[n][1] = *(const bf16x8*)(lds + (p) * (BNH * 16384) + boffb + (((nh) * 2 + n) * 16) * 128 + sb1); } }
#define MFMA_QUAD(mh, nh, BF) { \
  _Pragma("unroll") for (int m = 0; m < 4; m++) \
  _Pragma("unroll") for (int n = 0; n < 2; n++) \
  _Pragma("unroll") for (int kk = 0; kk < 2; kk++) \
    acc[(mh) * 4 + m][(nh) * 2 + n] = MF(afr[m][kk], BF[n][kk], \
                                         acc[(mh) * 4 + m][(nh) * 2 + n]); }
#define BAR_MFMA_OPEN() \
  __builtin_amdgcn_sched_barrier(0); \
  __builtin_amdgcn_s_barrier(); \
  asm volatile("s_waitcnt lgkmcnt(0)" ::: "memory"); \
  __builtin_amdgcn_sched_barrier(0); \
  __builtin_amdgcn_s_setprio(1)
#define PH_CLOSE() \
  __builtin_amdgcn_s_setprio(0); \
  __builtin_amdgcn_sched_barrier(0); \
  __builtin_amdgcn_s_barrier(); \
  __builtin_amdgcn_sched_barrier(0)
#define PH_CLOSE_VM(N) \
  __builtin_amdgcn_s_setprio(0); \
  asm volatile("s_waitcnt vmcnt(" #N ")" ::: "memory"); \
  __builtin_amdgcn_sched_barrier(0); \
  __builtin_amdgcn_s_barrier(); \
  __builtin_amdgcn_sched_barrier(0)

template <int BNH, int OUT_BF16, int BIAS_MODE, int FUSE>
__global__ __launch_bounds__(512, 2) void k_gemm256(
    const u16* __restrict__ A, const u16* __restrict__ BT,
    void* __restrict__ Cv, const float* __restrict__ bias,
    const float* __restrict__ finv,
    int K, int lda, int ldb, int ldc, long sA, long sB, long sC, float scale) {
  __shared__ __align__(16) char lds[65536 + BNH * 32768 + 1024];
  float* part = (float*)(lds + 65536 + BNH * 32768);

  int bxi = blockIdx.x, byi = blockIdx.y, bzi = blockIdx.z;
  xcd_swz(bxi, byi, bzi);
  const int tid = threadIdx.x, lane = tid & 63, wid = tid >> 6;
  const int wr = wid >> 2, wc = wid & 3;
  const int fr = lane & 15, kq = lane >> 4, fr7 = fr & 7;
  const int brow = byi * 256, bcol = bxi * (BNH * 128);
  const long z = bzi;

  if (FUSE == 3 && tid < 256) part[tid] = finv[z * 2048 + brow + tid];

  const int srow = tid >> 3;
  const int sslot = (tid & 7) ^ (srow & 7);
  const u16* gA = A + z * sA + (long)(brow + srow) * lda + sslot * 8;
  const u16* gB = BT + z * sB + (long)(bcol + srow) * ldb + sslot * 8;
  char* dA = lds + tid * 16;
  char* dB = lds + 65536 + tid * 16;

  const int aoffb = (wr * 128 + fr) * 128;
  const int boffb = 65536 + (wc * (BNH * 32) + fr) * 128;
  const int sb0 = (kq ^ fr7) * 16;
  const int sb1 = ((4 + kq) ^ fr7) * 16;

  f32x4 acc[8][2 * BNH];
  const f32x4 zero = {0.f, 0.f, 0.f, 0.f};
#pragma unroll
  for (int m = 0; m < 8; m++)
#pragma unroll
    for (int n = 0; n < 2 * BNH; n++) acc[m][n] = zero;

  bf16x8 afr[4][2], bf0[2][2], bf1[2][2];
  const int iters = K >> 7;

  if (BNH == 2) {
    SA(0, 0, 0, 0); SA(0, 0, 1, 0); SA(0, 1, 0, 0); SA(0, 1, 1, 0);
    SB(0, 0, 0, 0); SB(0, 0, 1, 0); SB(0, 1, 0, 0); SB(0, 1, 1, 0);
    SB(1, 0, 0, 1); SB(1, 0, 1, 1); SB(1, 1, 0, 1); SB(1, 1, 1, 1);
    asm volatile("s_waitcnt vmcnt(4)" ::: "memory");
    __builtin_amdgcn_sched_barrier(0);
    __builtin_amdgcn_s_barrier();
    for (int i = 0; i < iters; i++) {
      const int t1 = 2 * i + 1, p0 = 2 * i + 2, p1 = 2 * i + 3;
      const bool more = (i + 1 < iters);
      RD_A(0, 0); RD_B(0, 0, bf0);
      SA(1, 0, 0, t1); SA(1, 0, 1, t1);
      BAR_MFMA_OPEN(); MFMA_QUAD(0, 0, bf0); PH_CLOSE();
      RD_B(0, 1, bf1);
      SA(1, 1, 0, t1); SA(1, 1, 1, t1);
      BAR_MFMA_OPEN(); MFMA_QUAD(0, 1, bf1); PH_CLOSE();
      RD_A(0, 1);
      if (more) { SB(0, 0, 0, p0); SB(0, 0, 1, p0); }
      BAR_MFMA_OPEN(); MFMA_QUAD(1, 0, bf0); PH_CLOSE();
      if (more) { SB(0, 1, 0, p0); SB(0, 1, 1, p0); }
      BAR_MFMA_OPEN(); MFMA_QUAD(1, 1, bf1);
      if (more) { PH_CLOSE_VM(4); } else { PH_CLOSE_VM(0); }
      RD_A(1, 0); RD_B(1, 0, bf0);
      if (more) { SA(0, 0, 0, p0); SA(0, 0, 1, p0); }
      BAR_MFMA_OPEN(); MFMA_QUAD(0, 0, bf0); PH_CLOSE();
      RD_B(1, 1, bf1);
      if (more) { SA(0, 1, 0, p0); SA(0, 1, 1, p0); }
      BAR_MFMA_OPEN(); MFMA_QUAD(0, 1, bf1); PH_CLOSE();
      RD_A(1, 1);
      if (more) { SB(1, 0, 0, p1); SB(1, 0, 1, p1); }
      BAR_MFMA_OPEN(); MFMA_QUAD(1, 0, bf0); PH_CLOSE();
      if (more) { SB(1, 1, 0, p1); SB(1, 1, 1, p1); }
      BAR_MFMA_OPEN(); MFMA_QUAD(1, 1, bf1);
      if (more) { PH_CLOSE_VM(4); } else { PH_CLOSE_VM(0); }
    }
  } else {
    SA(0, 0, 0, 0); SA(0, 0, 1, 0); SA(0, 1, 0, 0); SA(0, 1, 1, 0);
    SB(0, 0, 0, 0); SB(0, 0, 1, 0);
    SB(1, 0, 0, 1); SB(1, 0, 1, 1);
    asm volatile("s_waitcnt vmcnt(2)" ::: "memory");
    __builtin_amdgcn_sched_barrier(0);
    __builtin_amdgcn_s_barrier();
    for (int i = 0; i < iters; i++) {
      const int t1 = 2 * i + 1, p0 = 2 * i + 2, p1 = 2 * i + 3;
      const bool more = (i + 1 < iters);
      RD_A(0, 0); RD_B(0, 0, bf0);
      SA(1, 0, 0, t1); SA(1, 0, 1, t1);
      BAR_MFMA_OPEN(); MFMA_QUAD(0, 0, bf0); PH_CLOSE();
      RD_A(0, 1);
      SA(1, 1, 0, t1); SA(1, 1, 1, t1);
      if (more) { SB(0, 0, 0, p0); SB(0, 0, 1, p0); }
      BAR_MFMA_OPEN(); MFMA_QUAD(1, 0, bf0);
      if (more) { PH_CLOSE_VM(2); } else { PH_CLOSE_VM(0); }
      RD_A(1, 0); RD_B(1, 0, bf1);
      if (more) { SA(0, 0, 0, p0); SA(0, 0, 1, p0); }
      BAR_MFMA_OPEN(); MFMA_QUAD(0, 0, bf1); PH_CLOSE();
      RD_A(1, 1);
      if (more) { SA(0, 1, 0, p0); SA(0, 1, 1, p0);
                  SB(1, 0, 0, p1); SB(1, 0, 1, p1); }
      BAR_MFMA_OPEN(); MFMA_QUAD(1, 0, bf1);
      if (more) { PH_CLOSE_VM(2); } else { PH_CLOSE_VM(0); }
    }
  }

  const long zC = z * sC;
#pragma unroll
  for (int mi = 0; mi < 8; mi++) {
    const int r0 = brow + wr * 128 + mi * 16 + kq * 4;
#pragma unroll
    for (int n = 0; n < 2 * BNH; n++) {
      const int c = bcol + wc * (BNH * 32) + n * 16 + fr;
#pragma unroll
      for (int r = 0; r < 4; r++) {
        float v = acc[mi][n][r] * scale;
        if (BIAS_MODE == 1) v += bias[c];
        if (BIAS_MODE == 2) v += bias[r0 + r];
        if (FUSE == 3) v = v * part[r0 + r - brow] + bias[c];
        const long off = zC + (long)(r0 + r) * ldc + c;
        if (OUT_BF16) ((u16*)Cv)[off] = f2bf(v);
        else          ((float*)Cv)[off] = v;
      }
    }
  }
}

extern "C" void kernel_launch(void* const* d_in, const int* in_sizes, int n_in,
                              void* d_out, int out_size, void* d_ws, size_t ws_size,
                              hipStream_t stream) {
  (void)in_sizes; (void)n_in; (void)out_size;
  const float* in1 = (const float*)d_in[0];
  const float* in2 = (const float*)d_in[1];
  const float* Wq  = (const float*)d_in[2];
  const float* bq  = (const float*)d_in[3];
  const float* Wk  = (const float*)d_in[4];
  const float* Wv  = (const float*)d_in[6];
  const float* bv  = (const float*)d_in[7];
  float* out = (float*)d_out;

  const size_t MB = 1024ull * 1024ull;
  if (ws_size < 100 * MB) return;

  char* ws = (char*)d_ws;
  u16* A1   = (u16*)(ws + 0);                 // [32768][512] bf16 X1
  u16* A2   = (u16*)(ws + 32 * MB);           // [32768][256] bf16 X2
  u16* Qp   = (u16*)(ws + 48 * MB);           // [32768][256] Q'
  u16* TX2  = (u16*)(ws + 64 * MB);           // [16][256][2048] X2^T
  u16* U    = (u16*)(ws + 80 * MB);           // [32768][256] P~·X2
  u16* Wqb  = (u16*)(ws + 96 * MB);           // [512][512]
  u16* Wkb  = (u16*)(ws + 96 * MB + 524288);  // [256][512]
  u16* WvT  = (u16*)(ws + 96 * MB + 786432);  // [512][256]
  u16* WT1  = (u16*)(ws + 97 * MB);           // [256][512] Wk·Wq^T
  float* bqp = (float*)(ws + 97 * MB + 262144);   // [256]
  float* Iv  = (float*)(ws + 97 * MB + 524288);   // [32768] inv row sums

  k_cvt<<<2048, 256, 0, stream>>>(in1, A1, 32768 * 512 / 4);
  k_cvt<<<256, 256, 0, stream>>>(Wq, Wqb, 512 * 512 / 4);
  k_cvt<<<128, 256, 0, stream>>>(Wk, Wkb, 256 * 512 / 4);
  k_cvt_t<<<dim3(8, 64, 16), dim3(32, 8), 0, stream>>>(in2, A2, TX2);
  k_transpose<<<dim3(16, 8), dim3(32, 8), 0, stream>>>(Wv, WvT, LENL, DIMD);
  // W' = Wk·Wq^T ; bq' = bq·Wk^T
  k_gemm256<2, 1, 0, 0><<<dim3(2, 1, 1), 512, 0, stream>>>(
      Wkb, Wqb, WT1, nullptr, nullptr, 512, 512, 512, 512, 0, 0, 0, 1.f);
  k_bqp<<<1, 256, 0, stream>>>(bq, Wk, bqp);
  // Q' = X1·W'^T + bq'
  k_gemm256<1, 1, 1, 0><<<dim3(2, 128, 1), 512, 0, stream>>>(
      A1, WT1, Qp, bqp, nullptr, 512, 512, 512, 256, 0, 0, 0, 1.f);
  // fused: S~ = exp(Q'·X2^T/sqrt(512)); U = S~·X2; Iv = 1/rowsum
  const float qk_scale = 0.044194173824159216f;
  k_fused_su<<<dim3(16, 16), 512, 0, stream>>>(Qp, A2, TX2, U, Iv, qk_scale);
  // out = Iv·(U·WvT^T) + bv
  k_gemm256<2, 0, 0, 3><<<dim3(2, 128, 1), 512, 0, stream>>>(
      U, WvT, out, bv, Iv, 256, 256, 256, 512, 0, 0, 0, 1.f);
}

// Round 11
// 184.223 us; speedup vs baseline: 1.0242x; 1.0242x over previous
//
#include <hip/hip_runtime.h>

// CrossAttention B=16, N1=N2=2048, D=512, L=256 — algebraic restructure +
// fused S~/U kernel, software-pipelined: QK(i) || PV(i-1) per barrier pair,
// counted vmcnt(8), S double-buffered. Round-9 64-key geometry (128B/512B
// rows, fr&7 swizzles) restored — round-10's 64B rows were a structural
// 4-way bank conflict.
//   W' = Wk·Wq^T, bq' = bq·Wk^T; Q' = X1·W'^T + bq'
//   fused: S = exp(Q'·X2^T/sqrt(512)) (LDS only), U = S·X2, Iv = 1/rowsum
//   out = Iv·(U·Wv) + bv

#define DIMD 512
#define LENL 256
#define BATCH 16
#define NQ 2048
#define NKV 2048

using bf16x8 = __attribute__((ext_vector_type(8))) __bf16;
using f32x4  = __attribute__((ext_vector_type(4))) float;
typedef unsigned short u16;

__device__ __forceinline__ u16 f2bf(float f) {
  union { float f; unsigned u; } x; x.f = f;
  return (u16)((x.u + 0x7fffu + ((x.u >> 16) & 1u)) >> 16);
}
__device__ __forceinline__ float bf2f(u16 b) {
  union { unsigned u; float f; } x; x.u = ((unsigned)b) << 16;
  return x.f;
}

__global__ __launch_bounds__(256) void k_cvt(const float* __restrict__ src,
                                             u16* __restrict__ dst, int n4) {
  int i = blockIdx.x * blockDim.x + threadIdx.x;
  int stride = gridDim.x * blockDim.x;
  for (; i < n4; i += stride) {
    float4 v = ((const float4*)src)[i];
    ushort4 o;
    o.x = f2bf(v.x); o.y = f2bf(v.y); o.z = f2bf(v.z); o.w = f2bf(v.w);
    ((ushort4*)dst)[i] = o;
  }
}

__global__ __launch_bounds__(256) void k_transpose(const float* __restrict__ W,
                                                   u16* __restrict__ WT,
                                                   int K, int N) {
  __shared__ float t[32][33];
  int bx = blockIdx.x * 32;
  int by = blockIdx.y * 32;
  int tx = threadIdx.x, ty = threadIdx.y;  // (32,8)
#pragma unroll
  for (int i = 0; i < 4; i++)
    t[ty + 8 * i][tx] = W[(size_t)(by + ty + 8 * i) * N + (bx + tx)];
  __syncthreads();
#pragma unroll
  for (int i = 0; i < 4; i++)
    WT[(size_t)(bx + ty + 8 * i) * K + (by + tx)] = f2bf(t[tx][ty + 8 * i]);
}

// fused: in2 f32 [z][2048][256] -> A2 bf16 (same layout) + TX2 bf16 [z][256][2048]
__global__ __launch_bounds__(256) void k_cvt_t(const float* __restrict__ in2,
                                               u16* __restrict__ A2,
                                               u16* __restrict__ TX2) {
  __shared__ u16 t[32][33];
  int bx = blockIdx.x * 32;  // L (256)
  int by = blockIdx.y * 32;  // keys (2048)
  long z = blockIdx.z;
  const float* s = in2 + z * (2048L * 256);
  u16* a = A2 + z * (2048L * 256);
  u16* d = TX2 + z * (256L * 2048);
  int tx = threadIdx.x, ty = threadIdx.y;  // (32,8)
#pragma unroll
  for (int i = 0; i < 4; i++) {
    u16 v = f2bf(s[(size_t)(by + ty + 8 * i) * 256 + (bx + tx)]);
    a[(size_t)(by + ty + 8 * i) * 256 + (bx + tx)] = v;
    t[ty + 8 * i][tx] = v;
  }
  __syncthreads();
#pragma unroll
  for (int i = 0; i < 4; i++)
    d[(size_t)(bx + ty + 8 * i) * 2048 + (by + tx)] = t[tx][ty + 8 * i];
}

__global__ __launch_bounds__(256) void k_bqp(const float* __restrict__ bq,
                                             const float* __restrict__ Wk,
                                             float* __restrict__ bqp) {
  int n = threadIdx.x;
  float s = 0.f;
  for (int o = 0; o < 512; o += 4) {
    float4 w = *(const float4*)&Wk[(size_t)n * 512 + o];
    float4 b = *(const float4*)&bq[o];
    s += w.x * b.x + w.y * b.y + w.z * b.z + w.w * b.w;
  }
  bqp[n] = s;
}

__device__ __forceinline__ void gl_lds16(const void* g, void* l) {
  __builtin_amdgcn_global_load_lds(
      (const __attribute__((address_space(1))) void*)g,
      (__attribute__((address_space(3))) void*)l, 16, 0, 0);
}

__device__ __forceinline__ void xcd_swz(int& bx, int& by, int& bz) {
  const int nx = gridDim.x, ny = gridDim.y, nz = gridDim.z;
  const long nwg = (long)nx * ny * nz;
  if (nwg & 7) return;
  long lin = (long)bx + (long)nx * ((long)by + (long)ny * bz);
  const long q = nwg >> 3;
  const long nl = (lin & 7) * q + (lin >> 3);
  bx = (int)(nl % nx);
  long r2 = nl / nx;
  by = (int)(r2 % ny);
  bz = (int)(r2 / ny);
}

#define MF(a, b, c) __builtin_amdgcn_mfma_f32_16x16x32_bf16(a, b, c, 0, 0, 0)

// ================== fused S~ / U kernel (QK || PV pipeline) ==================
// LDS: X2 dbuf 2x32K [0,64K) | TX2 dbuf 2x32K [64K,128K) | S dbuf 2x16K
// [128K,160K). part aliases S[0] (post-loop only). 160 KiB total, 1 block/CU.
// Per iter: stage X2(i+1)+TX2(i); vmcnt(8); barrier; QK(i)->S[i&1] and
// PV(i-1)<-S[(i-1)&1],TX2[(i-1)&1]; lgkmcnt(0); barrier.
__global__ __launch_bounds__(512, 2) void k_fused_su(
    const u16* __restrict__ Qp, const u16* __restrict__ X2g,
    const u16* __restrict__ TXg, u16* __restrict__ U,
    float* __restrict__ Iv, float scale) {
  __shared__ __align__(16) char lds[163840];
  float* part = (float*)(lds + 131072);  // aliases S[0]; used only post-loop

  int bxi = blockIdx.x, byi = blockIdx.y, bzi = blockIdx.z;
  xcd_swz(bxi, byi, bzi);
  const int tid = threadIdx.x, lane = tid & 63, wid = tid >> 6;
  const int fr = lane & 15, kq = lane >> 4, fr7 = fr & 7;
  const int row0 = bxi * 128;
  const long z = byi;
  const int kh = wid & 1, rq = wid >> 1;  // QK: 32 keys x 32 rows per wave
  const int wr = wid >> 2, wc = wid & 3;  // PV: 64 rows x 64 cols per wave

  // Q' fragments: rows rq*32 + ni*16 + fr, l-octet (kk*4+kq)*8
  bf16x8 qf[2][8];
  {
    const u16* qb = Qp + ((long)z * 2048 + row0 + rq * 32) * 256;
#pragma unroll
    for (int ni = 0; ni < 2; ni++)
#pragma unroll
      for (int kk = 0; kk < 8; kk++)
        qf[ni][kk] =
            *(const bf16x8*)(qb + (ni * 16 + fr) * 256 + kk * 32 + kq * 8);
  }

  const u16* gX2 = X2g + (long)z * (2048 * 256);
  const u16* gTX = TXg + (long)z * (256 * 2048);
  const int xrow = tid >> 5, xs = tid & 31;  // X2 tile: 64 rows x 512B
  const int trow = tid >> 3, ts = tid & 7;   // TX2 tile: 256 rows x 128B

#define STG_X2(ii, b) { \
  _Pragma("unroll") for (int p = 0; p < 4; p++) { \
    const int r_ = p * 16 + xrow; \
    gl_lds16(gX2 + ((long)(ii) * 64 + r_) * 256 + (xs ^ (r_ & 7)) * 8, \
             lds + (b) * 32768 + (p * 512 + tid) * 16); } }
#define STG_TX(ii, b) { \
  _Pragma("unroll") for (int p = 0; p < 4; p++) { \
    const int r_ = p * 64 + trow; \
    gl_lds16(gTX + (long)r_ * 2048 + (ii) * 64 + (ts ^ (r_ & 7)) * 8, \
             lds + 65536 + (b) * 32768 + (p * 512 + tid) * 16); } }

// QK(i): X2[xb] -> S[sb] (+ rowsum into rs0/rs1)
#define QK_BODY(xbuf, sbuf) { \
  f32x4 accS[2][2]; \
  accS[0][0] = zero; accS[0][1] = zero; accS[1][0] = zero; accS[1][1] = zero; \
  const char* xb = lds + (xbuf) * 32768; \
  _Pragma("unroll") for (int kk = 0; kk < 8; kk++) { \
    const int so = ((kk * 4 + kq) ^ fr7) << 4; \
    bf16x8 xf0 = *(const bf16x8*)(xb + (kh * 32 + fr) * 512 + so); \
    bf16x8 xf1 = *(const bf16x8*)(xb + (kh * 32 + 16 + fr) * 512 + so); \
    accS[0][0] = MF(xf0, qf[0][kk], accS[0][0]); \
    accS[0][1] = MF(xf0, qf[1][kk], accS[0][1]); \
    accS[1][0] = MF(xf1, qf[0][kk], accS[1][0]); \
    accS[1][1] = MF(xf1, qf[1][kk], accS[1][1]); \
  } \
  _Pragma("unroll") for (int mi = 0; mi < 2; mi++) \
  _Pragma("unroll") for (int ni = 0; ni < 2; ni++) { \
    u16 e[4]; float sum4 = 0.f; \
    _Pragma("unroll") for (int r = 0; r < 4; r++) { \
      float v = accS[mi][ni][r] * scale; \
      float ef = __expf(fminf(v, 30.f)); \
      e[r] = f2bf(ef); sum4 += bf2f(e[r]); \
    } \
    if (ni == 0) rs0 += sum4; else rs1 += sum4; \
    unsigned long long w = \
        (unsigned long long)((unsigned)e[0] | ((unsigned)e[1] << 16)) | \
        ((unsigned long long)((unsigned)e[2] | ((unsigned)e[3] << 16)) << 32); \
    const int row = rq * 32 + ni * 16 + fr; \
    const int inrow = (kh * 64 + mi * 32 + kq * 8) ^ (fr7 << 4); \
    *(unsigned long long*)(lds + 131072 + (sbuf) * 16384 + row * 128 + inrow) = w; \
  } }

// PV(i-1): S[sb] x TX2[tb] -> accU
#define PV_BODY(tbuf, sbuf) { \
  const char* tb = lds + 65536 + (tbuf) * 32768; \
  const char* sbase = lds + 131072 + (sbuf) * 16384; \
  _Pragma("unroll") for (int kk = 0; kk < 2; kk++) { \
    const int so = ((kk * 4 + kq) ^ fr7) << 4; \
    bf16x8 sf[4], tf[4]; \
    _Pragma("unroll") for (int m = 0; m < 4; m++) \
      sf[m] = *(const bf16x8*)(sbase + (wr * 64 + m * 16 + fr) * 128 + so); \
    _Pragma("unroll") for (int n = 0; n < 4; n++) \
      tf[n] = *(const bf16x8*)(tb + (wc * 64 + n * 16 + fr) * 128 + so); \
    _Pragma("unroll") for (int m = 0; m < 4; m++) \
    _Pragma("unroll") for (int n = 0; n < 4; n++) \
      accU[m][n] = MF(sf[m], tf[n], accU[m][n]); \
  } }

  f32x4 accU[4][4];
  const f32x4 zero = {0.f, 0.f, 0.f, 0.f};
#pragma unroll
  for (int m = 0; m < 4; m++)
#pragma unroll
    for (int n = 0; n < 4; n++) accU[m][n] = zero;
  float rs0 = 0.f, rs1 = 0.f;

  // prologue: X2(0), X2(1), TX2(0) = 12 ops in flight
  STG_X2(0, 0); STG_X2(1, 1); STG_TX(0, 0);
  asm volatile("s_waitcnt vmcnt(8)" ::: "memory");  // X2(0) landed
  __builtin_amdgcn_sched_barrier(0);
  __builtin_amdgcn_s_barrier();
  // peeled QK(0)
  __builtin_amdgcn_s_setprio(1);
  QK_BODY(0, 0);
  __builtin_amdgcn_s_setprio(0);
  asm volatile("s_waitcnt lgkmcnt(0)" ::: "memory");
  __builtin_amdgcn_sched_barrier(0);
  __builtin_amdgcn_s_barrier();
  __builtin_amdgcn_sched_barrier(0);

  for (int i = 1; i < 32; i++) {
    const int cur = i & 1, prv = cur ^ 1;
    const int pre = (i + 1 > 31) ? 31 : i + 1;  // dup-stage keeps count uniform
    STG_X2(pre, (i + 1) & 1);                   // dup target is a dead buffer
    STG_TX(i, cur);
    asm volatile("s_waitcnt vmcnt(8)" ::: "memory");  // X2(i), TX2(i-1) landed
    __builtin_amdgcn_sched_barrier(0);
    __builtin_amdgcn_s_barrier();
    __builtin_amdgcn_sched_barrier(0);
    __builtin_amdgcn_s_setprio(1);
    QK_BODY(cur, cur);   // independent of PV below: compiler interleaves
    PV_BODY(prv, prv);
    __builtin_amdgcn_s_setprio(0);
    asm volatile("s_waitcnt lgkmcnt(0)" ::: "memory");
    __builtin_amdgcn_sched_barrier(0);
    __builtin_amdgcn_s_barrier();
    __builtin_amdgcn_sched_barrier(0);
  }

  // epilogue: PV(31) (S[1], TX2[1]); TX2(31) needs full drain (it is newest)
  asm volatile("s_waitcnt vmcnt(0)" ::: "memory");
  __builtin_amdgcn_sched_barrier(0);
  __builtin_amdgcn_s_barrier();
  __builtin_amdgcn_s_setprio(1);
  PV_BODY(1, 1);
  __builtin_amdgcn_s_setprio(0);

#undef STG_X2
#undef STG_TX
#undef QK_BODY
#undef PV_BODY

  // rowsums -> Iv (part aliases S[0]; S is dead now)
  __syncthreads();
  if (tid < 128) part[tid] = 0.f;
  __syncthreads();
  {
    float s0 = rs0, s1 = rs1;
    s0 += __shfl_xor(s0, 16); s0 += __shfl_xor(s0, 32);
    s1 += __shfl_xor(s1, 16); s1 += __shfl_xor(s1, 32);
    if (lane < 16) {
      atomicAdd(&part[rq * 32 + lane], s0);
      atomicAdd(&part[rq * 32 + 16 + lane], s1);
    }
  }
  __syncthreads();
  if (tid < 128) Iv[z * 2048 + row0 + tid] = 1.f / part[tid];

  // U store (unnormalized bf16; out-GEMM applies Iv)
  u16* ub = U + ((long)z * 2048 + row0) * 256;
#pragma unroll
  for (int m = 0; m < 4; m++)
#pragma unroll
    for (int n = 0; n < 4; n++) {
      const int col = wc * 64 + n * 16 + fr;
#pragma unroll
      for (int r = 0; r < 4; r++) {
        const int row = wr * 64 + m * 16 + kq * 4 + r;
        ub[row * 256 + col] = f2bf(accU[m][n][r]);
      }
    }
}

// =============== 256-row 8-wave gemm_bt (round-7 proven form) =================
#define SA(p, h, l, T) \
  gl_lds16(gA + (long)((h) * 128 + (l) * 64) * lda + (T) * 64, \
           dA + (p) * 32768 + (h) * 16384 + (l) * 8192)
#define SB(p, h, l, T) \
  gl_lds16(gB + (long)((h) * 128 + (l) * 64) * ldb + (T) * 64, \
           dB + (p) * (BNH * 16384) + (h) * 16384 + (l) * 8192)
#define RD_A(p, mh) { _Pragma("unroll") for (int m = 0; m < 4; m++) { \
    afr[m][0] = *(const bf16x8*)(lds + (p) * 32768 + aoffb + ((mh) * 64 + m * 16) * 128 + sb0); \
    afr[m][1] = *(const bf16x8*)(lds + (p) * 32768 + aoffb + ((mh) * 64 + m * 16) * 128 + sb1); } }
#define RD_B(p, nh, BF) { _Pragma("unroll") for (int n = 0; n < 2; n++) { \
    BF[n][0] = *(const bf16x8*)(lds + (p) * (BNH * 16384) + boffb + (((nh) * 2 + n) * 16) * 128 + sb0); \
    BF[n][1] = *(const bf16x8*)(lds + (p) * (BNH * 16384) + boffb + (((nh) * 2 + n) * 16) * 128 + sb1); } }
#define MFMA_QUAD(mh, nh, BF) { \
  _Pragma("unroll") for (int m = 0; m < 4; m++) \
  _Pragma("unroll") for (int n = 0; n < 2; n++) \
  _Pragma("unroll") for (int kk = 0; kk < 2; kk++) \
    acc[(mh) * 4 + m][(nh) * 2 + n] = MF(afr[m][kk], BF[n][kk], \
                                         acc[(mh) * 4 + m][(nh) * 2 + n]); }
#define BAR_MFMA_OPEN() \
  __builtin_amdgcn_sched_barrier(0); \
  __builtin_amdgcn_s_barrier(); \
  asm volatile("s_waitcnt lgkmcnt(0)" ::: "memory"); \
  __builtin_amdgcn_sched_barrier(0); \
  __builtin_amdgcn_s_setprio(1)
#define PH_CLOSE() \
  __builtin_amdgcn_s_setprio(0); \
  __builtin_amdgcn_sched_barrier(0); \
  __builtin_amdgcn_s_barrier(); \
  __builtin_amdgcn_sched_barrier(0)
#define PH_CLOSE_VM(N) \
  __builtin_amdgcn_s_setprio(0); \
  asm volatile("s_waitcnt vmcnt(" #N ")" ::: "memory"); \
  __builtin_amdgcn_sched_barrier(0); \
  __builtin_amdgcn_s_barrier(); \
  __builtin_amdgcn_sched_barrier(0)

template <int BNH, int OUT_BF16, int BIAS_MODE, int FUSE>
__global__ __launch_bounds__(512, 2) void k_gemm256(
    const u16* __restrict__ A, const u16* __restrict__ BT,
    void* __restrict__ Cv, const float* __restrict__ bias,
    const float* __restrict__ finv,
    int K, int lda, int ldb, int ldc, long sA, long sB, long sC, float scale) {
  __shared__ __align__(16) char lds[65536 + BNH * 32768 + 1024];
  float* part = (float*)(lds + 65536 + BNH * 32768);

  int bxi = blockIdx.x, byi = blockIdx.y, bzi = blockIdx.z;
  xcd_swz(bxi, byi, bzi);
  const int tid = threadIdx.x, lane = tid & 63, wid = tid >> 6;
  const int wr = wid >> 2, wc = wid & 3;
  const int fr = lane & 15, kq = lane >> 4, fr7 = fr & 7;
  const int brow = byi * 256, bcol = bxi * (BNH * 128);
  const long z = bzi;

  if (FUSE == 3 && tid < 256) part[tid] = finv[z * 2048 + brow + tid];

  const int srow = tid >> 3;
  const int sslot = (tid & 7) ^ (srow & 7);
  const u16* gA = A + z * sA + (long)(brow + srow) * lda + sslot * 8;
  const u16* gB = BT + z * sB + (long)(bcol + srow) * ldb + sslot * 8;
  char* dA = lds + tid * 16;
  char* dB = lds + 65536 + tid * 16;

  const int aoffb = (wr * 128 + fr) * 128;
  const int boffb = 65536 + (wc * (BNH * 32) + fr) * 128;
  const int sb0 = (kq ^ fr7) * 16;
  const int sb1 = ((4 + kq) ^ fr7) * 16;

  f32x4 acc[8][2 * BNH];
  const f32x4 zero = {0.f, 0.f, 0.f, 0.f};
#pragma unroll
  for (int m = 0; m < 8; m++)
#pragma unroll
    for (int n = 0; n < 2 * BNH; n++) acc[m][n] = zero;

  bf16x8 afr[4][2], bf0[2][2], bf1[2][2];
  const int iters = K >> 7;

  if (BNH == 2) {
    SA(0, 0, 0, 0); SA(0, 0, 1, 0); SA(0, 1, 0, 0); SA(0, 1, 1, 0);
    SB(0, 0, 0, 0); SB(0, 0, 1, 0); SB(0, 1, 0, 0); SB(0, 1, 1, 0);
    SB(1, 0, 0, 1); SB(1, 0, 1, 1); SB(1, 1, 0, 1); SB(1, 1, 1, 1);
    asm volatile("s_waitcnt vmcnt(4)" ::: "memory");
    __builtin_amdgcn_sched_barrier(0);
    __builtin_amdgcn_s_barrier();
    for (int i = 0; i < iters; i++) {
      const int t1 = 2 * i + 1, p0 = 2 * i + 2, p1 = 2 * i + 3;
      const bool more = (i + 1 < iters);
      RD_A(0, 0); RD_B(0, 0, bf0);
      SA(1, 0, 0, t1); SA(1, 0, 1, t1);
      BAR_MFMA_OPEN(); MFMA_QUAD(0, 0, bf0); PH_CLOSE();
      RD_B(0, 1, bf1);
      SA(1, 1, 0, t1); SA(1, 1, 1, t1);
      BAR_MFMA_OPEN(); MFMA_QUAD(0, 1, bf1); PH_CLOSE();
      RD_A(0, 1);
      if (more) { SB(0, 0, 0, p0); SB(0, 0, 1, p0); }
      BAR_MFMA_OPEN(); MFMA_QUAD(1, 0, bf0); PH_CLOSE();
      if (more) { SB(0, 1, 0, p0); SB(0, 1, 1, p0); }
      BAR_MFMA_OPEN(); MFMA_QUAD(1, 1, bf1);
      if (more) { PH_CLOSE_VM(4); } else { PH_CLOSE_VM(0); }
      RD_A(1, 0); RD_B(1, 0, bf0);
      if (more) { SA(0, 0, 0, p0); SA(0, 0, 1, p0); }
      BAR_MFMA_OPEN(); MFMA_QUAD(0, 0, bf0); PH_CLOSE();
      RD_B(1, 1, bf1);
      if (more) { SA(0, 1, 0, p0); SA(0, 1, 1, p0); }
      BAR_MFMA_OPEN(); MFMA_QUAD(0, 1, bf1); PH_CLOSE();
      RD_A(1, 1);
      if (more) { SB(1, 0, 0, p1); SB(1, 0, 1, p1); }
      BAR_MFMA_OPEN(); MFMA_QUAD(1, 0, bf0); PH_CLOSE();
      if (more) { SB(1, 1, 0, p1); SB(1, 1, 1, p1); }
      BAR_MFMA_OPEN(); MFMA_QUAD(1, 1, bf1);
      if (more) { PH_CLOSE_VM(4); } else { PH_CLOSE_VM(0); }
    }
  } else {
    SA(0, 0, 0, 0); SA(0, 0, 1, 0); SA(0, 1, 0, 0); SA(0, 1, 1, 0);
    SB(0, 0, 0, 0); SB(0, 0, 1, 0);
    SB(1, 0, 0, 1); SB(1, 0, 1, 1);
    asm volatile("s_waitcnt vmcnt(2)" ::: "memory");
    __builtin_amdgcn_sched_barrier(0);
    __builtin_amdgcn_s_barrier();
    for (int i = 0; i < iters; i++) {
      const int t1 = 2 * i + 1, p0 = 2 * i + 2, p1 = 2 * i + 3;
      const bool more = (i + 1 < iters);
      RD_A(0, 0); RD_B(0, 0, bf0);
      SA(1, 0, 0, t1); SA(1, 0, 1, t1);
      BAR_MFMA_OPEN(); MFMA_QUAD(0, 0, bf0); PH_CLOSE();
      RD_A(0, 1);
      SA(1, 1, 0, t1); SA(1, 1, 1, t1);
      if (more) { SB(0, 0, 0, p0); SB(0, 0, 1, p0); }
      BAR_MFMA_OPEN(); MFMA_QUAD(1, 0, bf0);
      if (more) { PH_CLOSE_VM(2); } else { PH_CLOSE_VM(0); }
      RD_A(1, 0); RD_B(1, 0, bf1);
      if (more) { SA(0, 0, 0, p0); SA(0, 0, 1, p0); }
      BAR_MFMA_OPEN(); MFMA_QUAD(0, 0, bf1); PH_CLOSE();
      RD_A(1, 1);
      if (more) { SA(0, 1, 0, p0); SA(0, 1, 1, p0);
                  SB(1, 0, 0, p1); SB(1, 0, 1, p1); }
      BAR_MFMA_OPEN(); MFMA_QUAD(1, 0, bf1);
      if (more) { PH_CLOSE_VM(2); } else { PH_CLOSE_VM(0); }
    }
  }

  const long zC = z * sC;
#pragma unroll
  for (int mi = 0; mi < 8; mi++) {
    const int r0 = brow + wr * 128 + mi * 16 + kq * 4;
#pragma unroll
    for (int n = 0; n < 2 * BNH; n++) {
      const int c = bcol + wc * (BNH * 32) + n * 16 + fr;
#pragma unroll
      for (int r = 0; r < 4; r++) {
        float v = acc[mi][n][r] * scale;
        if (BIAS_MODE == 1) v += bias[c];
        if (BIAS_MODE == 2) v += bias[r0 + r];
        if (FUSE == 3) v = v * part[r0 + r - brow] + bias[c];
        const long off = zC + (long)(r0 + r) * ldc + c;
        if (OUT_BF16) ((u16*)Cv)[off] = f2bf(v);
        else          ((float*)Cv)[off] = v;
      }
    }
  }
}

extern "C" void kernel_launch(void* const* d_in, const int* in_sizes, int n_in,
                              void* d_out, int out_size, void* d_ws, size_t ws_size,
                              hipStream_t stream) {
  (void)in_sizes; (void)n_in; (void)out_size;
  const float* in1 = (const float*)d_in[0];
  const float* in2 = (const float*)d_in[1];
  const float* Wq  = (const float*)d_in[2];
  const float* bq  = (const float*)d_in[3];
  const float* Wk  = (const float*)d_in[4];
  const float* Wv  = (const float*)d_in[6];
  const float* bv  = (const float*)d_in[7];
  float* out = (float*)d_out;

  const size_t MB = 1024ull * 1024ull;
  if (ws_size < 100 * MB) return;

  char* ws = (char*)d_ws;
  u16* A1   = (u16*)(ws + 0);                 // [32768][512] bf16 X1
  u16* A2   = (u16*)(ws + 32 * MB);           // [32768][256] bf16 X2
  u16* Qp   = (u16*)(ws + 48 * MB);           // [32768][256] Q'
  u16* TX2  = (u16*)(ws + 64 * MB);           // [16][256][2048] X2^T
  u16* U    = (u16*)(ws + 80 * MB);           // [32768][256] P~·X2
  u16* Wqb  = (u16*)(ws + 96 * MB);           // [512][512]
  u16* Wkb  = (u16*)(ws + 96 * MB + 524288);  // [256][512]
  u16* WvT  = (u16*)(ws + 96 * MB + 786432);  // [512][256]
  u16* WT1  = (u16*)(ws + 97 * MB);           // [256][512] Wk·Wq^T
  float* bqp = (float*)(ws + 97 * MB + 262144);   // [256]
  float* Iv  = (float*)(ws + 97 * MB + 524288);   // [32768] inv row sums

  k_cvt<<<2048, 256, 0, stream>>>(in1, A1, 32768 * 512 / 4);
  k_cvt<<<256, 256, 0, stream>>>(Wq, Wqb, 512 * 512 / 4);
  k_cvt<<<128, 256, 0, stream>>>(Wk, Wkb, 256 * 512 / 4);
  k_cvt_t<<<dim3(8, 64, 16), dim3(32, 8), 0, stream>>>(in2, A2, TX2);
  k_transpose<<<dim3(16, 8), dim3(32, 8), 0, stream>>>(Wv, WvT, LENL, DIMD);
  // W' = Wk·Wq^T ; bq' = bq·Wk^T
  k_gemm256<2, 1, 0, 0><<<dim3(2, 1, 1), 512, 0, stream>>>(
      Wkb, Wqb, WT1, nullptr, nullptr, 512, 512, 512, 512, 0, 0, 0, 1.f);
  k_bqp<<<1, 256, 0, stream>>>(bq, Wk, bqp);
  // Q' = X1·W'^T + bq'
  k_gemm256<1, 1, 1, 0><<<dim3(2, 128, 1), 512, 0, stream>>>(
      A1, WT1, Qp, bqp, nullptr, 512, 512, 512, 256, 0, 0, 0, 1.f);
  // fused: S~ = exp(Q'·X2^T/sqrt(512)); U = S~·X2; Iv = 1/rowsum
  const float qk_scale = 0.044194173824159216f;
  k_fused_su<<<dim3(16, 16), 512, 0, stream>>>(Qp, A2, TX2, U, Iv, qk_scale);
  // out = Iv·(U·WvT^T) + bv
  k_gemm256<2, 0, 0, 3><<<dim3(2, 128, 1), 512, 0, stream>>>(
      U, WvT, out, bv, Iv, 256, 256, 256, 512, 0, 0, 0, 1.f);
}